// Round 8
// baseline (63.182 us; speedup 1.0000x reference)
//
#include <hip/hip_runtime.h>
#include <hip/hip_fp16.h>

#define NPOINTS 500000
#define RESOLUTION 128.0f
#define IDX_SIZE 524288u     // INDEX_TABLE_SIZE (2^19)
#define IDX_MASK 0x7FFFFu
#define FEAT_MASK 0xFFFFFu   // FEATURE_TABLE_SIZE-1 (2^20)
#define P1 2654435761u
#define P2 805459861u

typedef float    f4v __attribute__((ext_vector_type(4)));
typedef unsigned u2v __attribute__((ext_vector_type(2)));
typedef unsigned u4v __attribute__((ext_vector_type(4)));

constexpr unsigned mulinv32(unsigned a) {
    unsigned x = 1u;
    for (int i = 0; i < 6; ++i) x *= 2u - a * x;
    return x;
}
constexpr unsigned P2INV = mulinv32(P2);
static_assert(((P2INV * P2) & FEAT_MASK) == 1u, "bad inverse");

__device__ inline unsigned bf16pack(float a, float b) {
    unsigned ua = __float_as_uint(a); ua = (ua + 0x7FFFu + ((ua >> 16) & 1u)) >> 16;
    unsigned ub = __float_as_uint(b); ub = (ub + 0x7FFFu + ((ub >> 16) & 1u)) >> 16;
    return ua | (ub << 16);
}

__device__ inline unsigned f16pack(float a, float b) {
    __half2 h = __floats2half2_rn(a, b);
    union { __half2 h; unsigned u; } cv; cv.h = h;
    return cv.u;
}
__device__ inline float f16lo(unsigned u) {
    union { unsigned u; __half2 h; } cv; cv.u = u;
    return __low2float(cv.h);
}
__device__ inline float f16hi(unsigned u) {
    union { unsigned u; __half2 h; } cv; cv.u = u;
    return __high2float(cv.h);
}

// ---------------- Phase 1a (h-order): coalesced index_table read, softmax,
// normalized weights as 8xf16, scatter-store to E_y[y(h)] (fire-and-forget).
__global__ __launch_bounds__(256) void softmax_E(
    const float* __restrict__ index_table,
    u4v* __restrict__ E)
{
    unsigned h = blockIdx.x * blockDim.x + threadIdx.x;   // 0..2^19-1, grid exact

    const f4v* p = (const f4v*)(index_table + (size_t)h * 8u);
    f4v iw0 = p[0];
    f4v iw1 = p[1];
    float e[8] = { iw0.x, iw0.y, iw0.z, iw0.w, iw1.x, iw1.y, iw1.z, iw1.w };

    float mx = fmaxf(fmaxf(fmaxf(e[0], e[1]), fmaxf(e[2], e[3])),
                     fmaxf(fmaxf(e[4], e[5]), fmaxf(e[6], e[7])));
    float s = 0.f;
#pragma unroll
    for (int j = 0; j < 8; ++j) { e[j] = __expf(e[j] - mx); s += e[j]; }
    float inv = 1.0f / s;

    u4v ev;
    ev.x = f16pack(e[0] * inv, e[1] * inv);
    ev.y = f16pack(e[2] * inv, e[3] * inv);
    ev.z = f16pack(e[4] * inv, e[5] * inv);
    ev.w = f16pack(e[6] * inv, e[7] * inv);

    unsigned y = (h * P2) & FEAT_MASK;
    __builtin_nontemporal_store(ev, E + y);
}

// ---------------- Phase 1b (y-order): everything streams. 8 XOR-offset feature
// streams + coalesced E_y read; only the 8B F[h] store is scattered.
__global__ __launch_bounds__(256) void build_F_from_E(
    const f4v* __restrict__ ftp,
    const u4v* __restrict__ E,
    u2v* __restrict__ F)
{
    unsigned y = blockIdx.x * blockDim.x + threadIdx.x;   // 0..2^20-1
    unsigned h = (y * P2INV) & FEAT_MASK;
    if (h >= IDX_SIZE) return;

    u4v ev = E[y];                      // coalesced stream (15/16 line density)

    f4v fv[8];
#pragma unroll
    for (unsigned j = 0; j < 8; ++j) {
        unsigned cj = (j * P1) & FEAT_MASK;
        fv[j] = ftp[y ^ cj];
    }

    float q[8] = { f16lo(ev.x), f16hi(ev.x), f16lo(ev.y), f16hi(ev.y),
                   f16lo(ev.z), f16hi(ev.z), f16lo(ev.w), f16hi(ev.w) };

    float ax = 0.f, ay = 0.f, az = 0.f, aw = 0.f;
#pragma unroll
    for (int j = 0; j < 8; ++j) {
        ax = fmaf(fv[j].x, q[j], ax);
        ay = fmaf(fv[j].y, q[j], ay);
        az = fmaf(fv[j].z, q[j], az);
        aw = fmaf(fv[j].w, q[j], aw);
    }

    u2v packed;
    packed.x = bf16pack(ax, ay);
    packed.y = bf16pack(az, aw);
    __builtin_nontemporal_store(packed, F + h);
}

// ---------------- Phase 1 single-kernel variant (R6-proven) for mid-tier ws.
__global__ __launch_bounds__(256) void build_F_y(
    const f4v* __restrict__ ftp,
    const float* __restrict__ index_table,
    u2v* __restrict__ F)
{
    unsigned y = blockIdx.x * blockDim.x + threadIdx.x;
    unsigned h = (y * P2INV) & FEAT_MASK;
    if (h >= IDX_SIZE) return;

    const f4v* p = (const f4v*)(index_table + (size_t)h * 8u);
    f4v iw0 = p[0];
    f4v iw1 = p[1];

    f4v fv[8];
#pragma unroll
    for (unsigned j = 0; j < 8; ++j) {
        unsigned cj = (j * P1) & FEAT_MASK;
        fv[j] = ftp[y ^ cj];
    }

    float e[8] = { iw0.x, iw0.y, iw0.z, iw0.w, iw1.x, iw1.y, iw1.z, iw1.w };
    float mx = fmaxf(fmaxf(fmaxf(e[0], e[1]), fmaxf(e[2], e[3])),
                     fmaxf(fmaxf(e[4], e[5]), fmaxf(e[6], e[7])));
    float s = 0.f;
#pragma unroll
    for (int j = 0; j < 8; ++j) { e[j] = __expf(e[j] - mx); s += e[j]; }

    float ax = 0.f, ay = 0.f, az = 0.f, aw = 0.f;
#pragma unroll
    for (int j = 0; j < 8; ++j) {
        ax = fmaf(fv[j].x, e[j], ax);
        ay = fmaf(fv[j].y, e[j], ay);
        az = fmaf(fv[j].z, e[j], az);
        aw = fmaf(fv[j].w, e[j], aw);
    }
    float inv = 1.0f / s;
    u2v packed;
    packed.x = bf16pack(ax * inv, ay * inv);
    packed.y = bf16pack(az * inv, aw * inv);
    F[h] = packed;
}

// ---------------- Phase 2: corner-per-lane (4M lanes, 61 waves/SIMD for latency
// hiding). One 8B F-gather per lane; 8-lane butterfly reduce; lane0 writes 16B.
__global__ __launch_bounds__(256) void interp_corner(
    const float* __restrict__ x,
    const u2v* __restrict__ F,
    f4v* __restrict__ out)
{
    int tid = blockIdx.x * blockDim.x + threadIdx.x;   // grid exact: 4M
    int p = tid >> 3;
    int corner = tid & 7;

    float xs0 = x[p * 3 + 0] * RESOLUTION;
    float xs1 = x[p * 3 + 1] * RESOLUTION;
    float xs2 = x[p * 3 + 2] * RESOLUTION;
    int i0 = (int)xs0, i1 = (int)xs1, i2 = (int)xs2;
    float f0 = xs0 - (float)i0, f1 = xs1 - (float)i1, f2 = xs2 - (float)i2;

    unsigned b0 = corner & 1u, b1 = (corner >> 1) & 1u, b2 = (corner >> 2) & 1u;
    unsigned h = (((unsigned)i0 + b0) ^ (((unsigned)i1 + b1) * P1)
                  ^ (((unsigned)i2 + b2) * P2)) & IDX_MASK;
    float w = (b0 ? f0 : 1.0f - f0) * (b1 ? f1 : 1.0f - f1) * (b2 ? f2 : 1.0f - f2);

    u2v fv = F[h];
    float ax = __uint_as_float(fv.x << 16) * w;
    float ay = __uint_as_float(fv.x & 0xFFFF0000u) * w;
    float az = __uint_as_float(fv.y << 16) * w;
    float aw = __uint_as_float(fv.y & 0xFFFF0000u) * w;

#pragma unroll
    for (int m = 1; m < 8; m <<= 1) {
        ax += __shfl_xor(ax, m);
        ay += __shfl_xor(ay, m);
        az += __shfl_xor(az, m);
        aw += __shfl_xor(aw, m);
    }
    if (corner == 0) {
        f4v o = { ax, ay, az, aw };
        out[p] = o;
    }
}

// ---------------- Fallback (proven R1 kernel) if ws is too small ----------------
__global__ __launch_bounds__(256) void hashgrid_fwd(
    const float* __restrict__ x,
    const float* __restrict__ feature_table,
    const float* __restrict__ index_table,
    float* __restrict__ out)
{
    int tid = blockIdx.x * blockDim.x + threadIdx.x;
    int p = tid >> 3;
    int corner = tid & 7;
    if (p >= NPOINTS) return;

    float xs0 = x[p * 3 + 0] * RESOLUTION;
    float xs1 = x[p * 3 + 1] * RESOLUTION;
    float xs2 = x[p * 3 + 2] * RESOLUTION;
    int i0 = (int)xs0, i1 = (int)xs1, i2 = (int)xs2;
    float f0 = xs0 - (float)i0, f1 = xs1 - (float)i1, f2 = xs2 - (float)i2;

    unsigned b0 = corner & 1u, b1 = (corner >> 1) & 1u, b2 = (corner >> 2) & 1u;
    float w0 = b0 ? f0 : 1.0f - f0;
    float w1 = b1 ? f1 : 1.0f - f1;
    float w2 = b2 ? f2 : 1.0f - f2;
    float w = w0 * w1 * w2;

    unsigned h = (((unsigned)i0 + b0) ^ (((unsigned)i1 + b1) * P1)
                  ^ (((unsigned)i2 + b2) * P2)) & IDX_MASK;

    const float4* itp = (const float4*)(index_table + (size_t)h * 8u);
    float4 iw0 = itp[0];
    float4 iw1 = itp[1];
    float e0 = iw0.x, e1 = iw0.y, e2 = iw0.z, e3 = iw0.w;
    float e4 = iw1.x, e5 = iw1.y, e6 = iw1.z, e7 = iw1.w;

    float mx = fmaxf(fmaxf(fmaxf(e0, e1), fmaxf(e2, e3)),
                     fmaxf(fmaxf(e4, e5), fmaxf(e6, e7)));
    e0 = __expf(e0 - mx); e1 = __expf(e1 - mx);
    e2 = __expf(e2 - mx); e3 = __expf(e3 - mx);
    e4 = __expf(e4 - mx); e5 = __expf(e5 - mx);
    e6 = __expf(e6 - mx); e7 = __expf(e7 - mx);
    float s = ((e0 + e1) + (e2 + e3)) + ((e4 + e5) + (e6 + e7));

    unsigned hp2 = h * P2;
    const float4* ftp = (const float4*)feature_table;
    float ax = 0.f, ay = 0.f, az = 0.f, aw = 0.f;
    float ej[8] = {e0, e1, e2, e3, e4, e5, e6, e7};
#pragma unroll
    for (unsigned j = 0; j < 8; ++j) {
        unsigned a = ((j * P1) ^ hp2) & FEAT_MASK;
        float4 ft = ftp[a];
        ax = fmaf(ft.x, ej[j], ax);
        ay = fmaf(ft.y, ej[j], ay);
        az = fmaf(ft.z, ej[j], az);
        aw = fmaf(ft.w, ej[j], aw);
    }

    float scale = w / s;
    ax *= scale; ay *= scale; az *= scale; aw *= scale;

#pragma unroll
    for (int m = 1; m < 8; m <<= 1) {
        ax += __shfl_xor(ax, m);
        ay += __shfl_xor(ay, m);
        az += __shfl_xor(az, m);
        aw += __shfl_xor(aw, m);
    }
    if (corner == 0) {
        ((float4*)out)[p] = make_float4(ax, ay, az, aw);
    }
}

extern "C" void kernel_launch(void* const* d_in, const int* in_sizes, int n_in,
                              void* d_out, int out_size, void* d_ws, size_t ws_size,
                              hipStream_t stream) {
    const float* x  = (const float*)d_in[0];
    const float* ft = (const float*)d_in[1];
    const float* it = (const float*)d_in[2];

    const size_t F_BYTES = (size_t)IDX_SIZE * 8u;            // 4 MiB
    const size_t E_BYTES = (size_t)(1u << 20) * 16u;         // 16 MiB

    if (ws_size >= F_BYTES + E_BYTES) {
        u2v* F = (u2v*)d_ws;
        u4v* E = (u4v*)((char*)d_ws + F_BYTES);
        hipLaunchKernelGGL(softmax_E, dim3(IDX_SIZE / 256), dim3(256), 0, stream,
                           it, E);
        hipLaunchKernelGGL(build_F_from_E, dim3((1u << 20) / 256), dim3(256), 0, stream,
                           (const f4v*)ft, E, F);
        hipLaunchKernelGGL(interp_corner, dim3(NPOINTS * 8 / 256), dim3(256), 0, stream,
                           x, F, (f4v*)d_out);
    } else if (ws_size >= F_BYTES) {
        u2v* F = (u2v*)d_ws;
        hipLaunchKernelGGL(build_F_y, dim3((1u << 20) / 256), dim3(256), 0, stream,
                           (const f4v*)ft, it, F);
        hipLaunchKernelGGL(interp_corner, dim3(NPOINTS * 8 / 256), dim3(256), 0, stream,
                           x, F, (f4v*)d_out);
    } else {
        const int total = NPOINTS * 8;
        hipLaunchKernelGGL(hashgrid_fwd, dim3((total + 255) / 256), dim3(256), 0, stream,
                           x, ft, it, (float*)d_out);
    }
}